// Round 12
// baseline (310.747 us; speedup 1.0000x reference)
//
#include <hip/hip_runtime.h>
#include <math.h>

typedef __attribute__((ext_vector_type(8))) short short8;
typedef __attribute__((ext_vector_type(4))) float f32x4;

__device__ __forceinline__ unsigned f2bf(float f) {
  unsigned u = __float_as_uint(f);
  return (u + 0x7FFFu + ((u >> 16) & 1u)) >> 16;
}
__device__ __forceinline__ unsigned pk2(float lo, float hi) {
  return f2bf(lo) | (f2bf(hi) << 16);
}

// ---------------- workspace layout (float offsets) ----------------
#define WS_X1    0                    // 16384*200
#define WS_W2P   3328000              // w2pre: 128*48*320 bf16 shorts
#define WS_AS    4966400              // 1024
#define WS_AD    4967424              // 1024
#define WS_WEFB  4968464              // weffB: 48*32 bf16
#define WS_S1    4969664              // 40
#define WS_SH1   4969704              // 40
#define WS_S2    4969744              // 40
#define WS_SH2   4969784              // 40
#define WS_H     4970496              // 1024*256 fp32
#define WS_P     5232640              // P bf16: 1024*1024 ushorts
#define WS_HT    5494784              // hT bf16: 256*1024 ushorts
#define WS_Y3P   WS_P                 // 16*32*1400 fp32 (overlays P/HT; dead by k3)
#define WS_Y5    8400768              // 16*1400
#define WS_ZP    8455936              // 7*16*1024
#define WS_Z2P   8570624              // 8*16*1024
#define WS_WPT   8701696              // 256*224 bf16
// end 8,730,368 floats = 34.9 MB

// ---------------- k0: params + wpadT + weffB + w2pre ----------------
__global__ __launch_bounds__(256) void k0_prep(const float* __restrict__ gat_W,
                        const float* __restrict__ conv1_w, const float* __restrict__ conv1_b,
                        const float* __restrict__ bn1_g, const float* __restrict__ bn1_b,
                        const float* __restrict__ bn1_m, const float* __restrict__ bn1_v,
                        const float* __restrict__ conv2_b,
                        const float* __restrict__ bn2_g, const float* __restrict__ bn2_b,
                        const float* __restrict__ bn2_m, const float* __restrict__ bn2_v,
                        const float* __restrict__ w2,
                        float* __restrict__ ws) {
  int bx = blockIdx.x, t = threadIdx.x;
  if (bx < 224) {
    unsigned short* wpt = (unsigned short*)(ws + WS_WPT);
    int idx = bx * 256 + t;
    int n = idx / 224, k = idx % 224;
    float v = (n < 200 && k < 200) ? gat_W[k * 200 + n] : 0.f;
    wpt[idx] = (unsigned short)f2bf(v);
    return;
  }
  if (bx == 224) {
    if (t < 48) {
      unsigned short* wb = (unsigned short*)(ws + WS_WEFB);
      float wv[30];
      if (t < 40) {
        for (int j = 0; j < 30; ++j) {
          float s = 0.f;
          for (int tt = 0; tt < 5; ++tt) {
            int k = j - tt;
            if (k >= 0 && k < 26) s += conv1_w[t * 26 + k];
          }
          wv[j] = s * 0.2f;
        }
      }
      for (int k = 0; k < 32; ++k)
        wb[t * 32 + k] = (unsigned short)f2bf((t < 40 && k < 30) ? wv[k] : 0.f);
    }
    if (t < 40) {
      float s1 = bn1_g[t] * rsqrtf(bn1_v[t] + 1e-5f);
      ws[WS_S1 + t] = s1;
      ws[WS_SH1 + t] = bn1_b[t] + (conv1_b[t] - bn1_m[t]) * s1;
      float s2 = bn2_g[t] * rsqrtf(bn2_v[t] + 1e-5f);
      ws[WS_S2 + t] = s2;
      ws[WS_SH2 + t] = bn2_b[t] + (conv2_b[t] - bn2_m[t]) * s2;
    }
    return;
  }
  __shared__ unsigned short lds[2560];
  int q = bx - 225;
  int c8 = q / 6, o0 = (q % 6) * 8;
  unsigned short* w2p = (unsigned short*)(ws + WS_W2P);
#pragma unroll
  for (int i = 0; i < 10; ++i) {
    int e = i * 256 + t;
    int o = e / 320, rr = e % 320;
    int c = rr / 8, nl = rr % 8;
    int oa = o0 + o;
    float v = (oa < 40) ? w2[(oa * 40 + c) * 1024 + c8 * 8 + nl] : 0.f;
    lds[o * 320 + nl * 40 + c] = (unsigned short)f2bf(v);
  }
  __syncthreads();
  uint4* src = (uint4*)lds;
  uint4* dst = (uint4*)(w2p + (c8 * 48 + o0) * 320);
  for (int i = t; i < 320; i += 256) dst[i] = src[i];
}

// ---------------- k1: MFMA GEMM, 256 blocks ----------------
__global__ __launch_bounds__(256) void k1_mfma(const float* __restrict__ x,
                                               const unsigned short* __restrict__ wpt,
                                               const float* __restrict__ gat_b,
                                               float* __restrict__ h,
                                               unsigned short* __restrict__ hT,
                                               float* __restrict__ x1) {
  __shared__ unsigned short As[64 * 232];
  __shared__ unsigned short Bt[64 * 232];
  int t = threadIdx.x;
  int wave = t >> 6, lane = t & 63;
  int m16 = lane & 15, quad = lane >> 4;
  int row0 = blockIdx.x * 64;
  {
    int m = t >> 2, kq = (t & 3) * 8;
    const float* xr = x + (row0 + m) * 200;
#pragma unroll
    for (int s = 0; s < 7; ++s) {
      int kg = s * 32 + kq;
      uint4 pv;
      if (kg + 8 <= 200) {
        float4 a = *(const float4*)(xr + kg);
        float4 b = *(const float4*)(xr + kg + 4);
        pv.x = pk2(a.x, a.y); pv.y = pk2(a.z, a.w);
        pv.z = pk2(b.x, b.y); pv.w = pk2(b.z, b.w);
      } else {
        float e[8];
#pragma unroll
        for (int q = 0; q < 8; ++q) e[q] = (kg + q < 200) ? xr[kg + q] : 0.f;
        pv.x = pk2(e[0], e[1]); pv.y = pk2(e[2], e[3]);
        pv.z = pk2(e[4], e[5]); pv.w = pk2(e[6], e[7]);
      }
      *(uint4*)&As[m * 232 + kg] = pv;
    }
  }
  __syncthreads();
  for (int c = 0; c < 4; ++c) {
    int n0 = c * 64;
    for (int i = t; i < 1792; i += 256) {
      int row = i / 28, ch = i % 28;
      *(short8*)&Bt[row * 232 + ch * 8] = *(const short8*)&wpt[(n0 + row) * 224 + ch * 8];
    }
    __syncthreads();
    f32x4 acc[4];
#pragma unroll
    for (int nt = 0; nt < 4; ++nt) acc[nt] = (f32x4){0.f, 0.f, 0.f, 0.f};
#pragma unroll
    for (int s = 0; s < 7; ++s) {
      short8 af = *(const short8*)&As[(wave * 16 + m16) * 232 + s * 32 + quad * 8];
      int kb = s * 32 + quad * 8;
#pragma unroll
      for (int nt = 0; nt < 4; ++nt) {
        short8 bf = *(const short8*)&Bt[(nt * 16 + m16) * 232 + kb];
        acc[nt] = __builtin_amdgcn_mfma_f32_16x16x32_bf16(af, bf, acc[nt], 0, 0, 0);
      }
    }
    if (blockIdx.x < 16) {
#pragma unroll
      for (int nt = 0; nt < 4; ++nt) {
        int col = n0 + nt * 16 + m16;
#pragma unroll
        for (int r = 0; r < 4; ++r) {
          int row = row0 + wave * 16 + quad * 4 + r;
          float v = acc[nt][r];
          h[row * 256 + col] = v;
          hT[col * 1024 + row] = (unsigned short)f2bf(v);
        }
      }
    } else {
#pragma unroll
      for (int nt = 0; nt < 4; ++nt) {
        int col = n0 + nt * 16 + m16;
        if (col < 200) {
          float gb = gat_b[col];
#pragma unroll
          for (int r = 0; r < 4; ++r) {
            int row = row0 + wave * 16 + quad * 4 + r;
            x1[row * 200 + col] = x[row * 200 + col] + acc[nt][r] + gb;
          }
        }
      }
    }
    __syncthreads();
  }
}

// ---------------- k1b: attention scores — wave-per-row ----------------
__global__ __launch_bounds__(256) void k1b_scores(const float* __restrict__ h,
                                                  const float* __restrict__ att_src,
                                                  const float* __restrict__ att_dst,
                                                  float* __restrict__ as_,
                                                  float* __restrict__ ad_) {
  int t = threadIdx.x;
  int wave = t >> 6, lane = t & 63;
  int r = blockIdx.x * 4 + wave;
  float s = 0.f, d = 0.f;
  if (lane < 50) {
    float4 v = *(const float4*)(h + r * 256 + lane * 4);
    float4 a = *(const float4*)(att_src + lane * 4);
    float4 dd = *(const float4*)(att_dst + lane * 4);
    s = v.x * a.x + v.y * a.y + v.z * a.z + v.w * a.w;
    d = v.x * dd.x + v.y * dd.y + v.z * dd.z + v.w * dd.w;
  }
#pragma unroll
  for (int off = 32; off > 0; off >>= 1) {
    s += __shfl_down(s, off);
    d += __shfl_down(d, off);
  }
  if (lane == 0) {
    as_[r] = s;
    ad_[r] = d;
  }
}

// ---------------- kP: normalized softmax P -> bf16 ----------------
__global__ __launch_bounds__(256) void kP(const float* __restrict__ as_,
                                          const float* __restrict__ ad_,
                                          unsigned short* __restrict__ Pb) {
  __shared__ float rb[256];
  int t = threadIdx.x, i = blockIdx.x;
  float a0 = as_[t], a1 = as_[256 + t], a2 = as_[512 + t], a3 = as_[768 + t];
  rb[t] = fmaxf(fmaxf(a0, a1), fmaxf(a2, a3));
  __syncthreads();
  for (int st = 128; st > 0; st >>= 1) {
    if (t < st) rb[t] = fmaxf(rb[t], rb[t + st]);
    __syncthreads();
  }
  float maxs = rb[0];
  __syncthreads();
  float ad = ad_[i];
  float mv = maxs + ad;
  float M = mv >= 0.f ? mv : 0.2f * mv;
  float av[4] = {a0, a1, a2, a3};
  float p[4];
  float s = 0.f;
#pragma unroll
  for (int q = 0; q < 4; ++q) {
    float v = av[q] + ad;
    float l = v >= 0.f ? v : 0.2f * v;
    p[q] = __expf(l - M);
    s += p[q];
  }
  rb[t] = s;
  __syncthreads();
  for (int st = 128; st > 0; st >>= 1) {
    if (t < st) rb[t] += rb[t + st];
    __syncthreads();
  }
  float inv = 1.f / rb[0];
#pragma unroll
  for (int q = 0; q < 4; ++q)
    Pb[i * 1024 + q * 256 + t] = (unsigned short)f2bf(p[q] * inv);
}

// ---------------- kAttn v2: full-K MFMA + fused residual -> x1 rows [0,1024) ----------------
// grid (16 i-tiles, 4 f-tiles), block 256 (4 waves). No ap, no reduce kernel.
__global__ __launch_bounds__(256) void kAttn(const unsigned short* __restrict__ Pb,
                                             const unsigned short* __restrict__ hT,
                                             const float* __restrict__ x,
                                             const float* __restrict__ gat_b,
                                             float* __restrict__ x1) {
  int t = threadIdx.x;
  int wave = t >> 6, lane = t & 63;
  int l15 = lane & 15, quad = lane >> 4;
  int i0 = blockIdx.x * 64, f0 = blockIdx.y * 64;
  int arow = i0 + wave * 16 + l15;
  f32x4 acc[4];
#pragma unroll
  for (int nt = 0; nt < 4; ++nt) acc[nt] = (f32x4){0.f, 0.f, 0.f, 0.f};
#pragma unroll 4
  for (int ks = 0; ks < 32; ++ks) {
    int koff = ks * 32 + quad * 8;
    short8 a = *(const short8*)&Pb[arow * 1024 + koff];
#pragma unroll
    for (int nt = 0; nt < 4; ++nt) {
      short8 bf = *(const short8*)&hT[(f0 + nt * 16 + l15) * 1024 + koff];
      acc[nt] = __builtin_amdgcn_mfma_f32_16x16x32_bf16(a, bf, acc[nt], 0, 0, 0);
    }
  }
#pragma unroll
  for (int nt = 0; nt < 4; ++nt) {
    int col = f0 + nt * 16 + l15;
    if (col < 200) {
      float gb = gat_b[col];
#pragma unroll
      for (int r = 0; r < 4; ++r) {
        int row = i0 + wave * 16 + quad * 4 + r;
        x1[row * 200 + col] = x[row * 200 + col] + acc[nt][r] + gb;
      }
    }
  }
}

// ---------------- k3 v11: 4 chunks/block, t2 aliases tA (LDS 30 KB) ----------------
// grid (16 b, 32 nc), block 320 (5 waves). conv2 acc persists across chunks.
__global__ __launch_bounds__(320, 2) void k3_conv(const float* __restrict__ x1,
                                                  const unsigned short* __restrict__ w2pre,
                                                  const unsigned short* __restrict__ weffB,
                                                  const float* __restrict__ ws,
                                                  float* __restrict__ y3p) {
  __shared__ __align__(16) char smem[30016];
  float* xbp = (float*)smem;                              // 8 x 200 fp32 (6400 B)
  unsigned short* tA = (unsigned short*)(smem + 6400);    // 288 x 32 bf16 (18432 B)
  unsigned short* t2 = (unsigned short*)(smem + 6400);    // 36 x 328 bf16 — ALIASES tA
  int t = threadIdx.x;
  int b = blockIdx.x, nc = blockIdx.y;
  int wave = t >> 6, lane = t & 63;
  int l15 = lane & 15, quad = lane >> 4;
  // conv1 B fragments + bn1 params (persist)
  short8 bw[3];
  float s1v[3], sh1v[3];
#pragma unroll
  for (int nt = 0; nt < 3; ++nt) {
    bw[nt] = *(const short8*)&weffB[(nt * 16 + l15) * 32 + quad * 8];
    int c = nt * 16 + l15;
    s1v[nt] = (c < 40) ? ws[WS_S1 + c] : 0.f;
    sh1v[nt] = (c < 40) ? ws[WS_SH1 + c] : 0.f;
  }
  f32x4 acc[3][3];
#pragma unroll
  for (int mt = 0; mt < 3; ++mt)
#pragma unroll
    for (int nt = 0; nt < 3; ++nt) acc[mt][nt] = (f32x4){0.f, 0.f, 0.f, 0.f};
  int mt0 = wave * 4;
  int nmt = wave < 4 ? 4 : 2;
  // prologue: stage chunk 0
  {
    int n0 = nc * 32;
    for (int i = t; i < 400; i += 320) {
      int nn = i / 50, q = i % 50;
      ((float4*)(xbp + nn * 200))[q] = ((const float4*)(x1 + (b * 1024 + n0 + nn) * 200))[q];
    }
  }
  __syncthreads();
  for (int it = 0; it < 4; ++it) {
    int c8 = nc * 4 + it;
    // A-pack: xbp -> tA
    if (t < 280) {
      int nn = t / 35, p = t % 35;
      const float* xr = xbp + nn * 200 + p * 5;
      uint pv[16];
#pragma unroll
      for (int kk = 0; kk < 15; ++kk) pv[kk] = pk2(xr[kk * 2], xr[kk * 2 + 1]);
      pv[15] = 0u;
      uint4* dst = (uint4*)(tA + t * 32);
      dst[0] = make_uint4(pv[0], pv[1], pv[2], pv[3]);
      dst[1] = make_uint4(pv[4], pv[5], pv[6], pv[7]);
      dst[2] = make_uint4(pv[8], pv[9], pv[10], pv[11]);
      dst[3] = make_uint4(pv[12], pv[13], pv[14], pv[15]);
    } else if (t < 288) {
      uint4 z = make_uint4(0u, 0u, 0u, 0u);
      uint4* dst = (uint4*)(tA + t * 32);
      dst[0] = z; dst[1] = z; dst[2] = z; dst[3] = z;
    }
    __syncthreads();
    // conv1 MFMA -> hold C in regs
    f32x4 c4[4][3];
    for (int mi = 0; mi < nmt; ++mi) {
      short8 a = *(const short8*)&tA[((mt0 + mi) * 16 + l15) * 32 + quad * 8];
#pragma unroll
      for (int nt = 0; nt < 3; ++nt) {
        f32x4 z = {0.f, 0.f, 0.f, 0.f};
        c4[mi][nt] = __builtin_amdgcn_mfma_f32_16x16x32_bf16(a, bw[nt], z, 0, 0, 0);
      }
    }
    __syncthreads();  // all tA reads done; t2 may now overwrite
    // epilogue: bn1+elu -> t2
    for (int mi = 0; mi < nmt; ++mi) {
      int mt = mt0 + mi;
#pragma unroll
      for (int nt = 0; nt < 3; ++nt) {
        int c = nt * 16 + l15;
        if (c >= 40) continue;
#pragma unroll
        for (int r = 0; r < 4; ++r) {
          int m = mt * 16 + quad * 4 + r;
          if (m < 280) {
            float v = c4[mi][nt][r] * s1v[nt] + sh1v[nt];
            float e = v > 0.f ? v : __expf(v) - 1.f;
            int p = m % 35, nn = m / 35;
            t2[p * 328 + nn * 40 + c] = (unsigned short)f2bf(e);
          }
        }
      }
    }
    __syncthreads();  // t2 ready
    // stage next chunk's x while conv2 runs
    if (it < 3) {
      int n0n = nc * 32 + (it + 1) * 8;
      for (int i = t; i < 400; i += 320) {
        int nn = i / 50, q = i % 50;
        ((float4*)(xbp + nn * 200))[q] = ((const float4*)(x1 + (b * 1024 + n0n + nn) * 200))[q];
      }
    }
    // conv2 MFMA accumulate
    const unsigned short* bbase = w2pre + c8 * 48 * 320;
#pragma unroll
    for (int ks = 0; ks < 2; ++ks) {
      int koff = wave * 64 + ks * 32 + quad * 8;
      short8 a[3], bb[3];
#pragma unroll
      for (int mt = 0; mt < 3; ++mt) {
        int row = mt * 16 + l15;
        row = row > 35 ? 35 : row;
        a[mt] = *(const short8*)&t2[row * 328 + koff];
      }
#pragma unroll
      for (int nt = 0; nt < 3; ++nt)
        bb[nt] = *(const short8*)&bbase[(nt * 16 + l15) * 320 + koff];
#pragma unroll
      for (int mt = 0; mt < 3; ++mt)
#pragma unroll
        for (int nt = 0; nt < 3; ++nt)
          acc[mt][nt] = __builtin_amdgcn_mfma_f32_16x16x32_bf16(a[mt], bb[nt], acc[mt][nt], 0, 0, 0);
    }
    __syncthreads();  // t2 reads done before next A-pack
  }
  // cross-wave C reduction (red overlays smem; all dead)
  float* red0 = (float*)smem;
  float* red1 = red0 + 48 * 49;
  if (wave < 2) {
    float* r = wave ? red1 : red0;
#pragma unroll
    for (int mt = 0; mt < 3; ++mt)
#pragma unroll
      for (int nt = 0; nt < 3; ++nt)
#pragma unroll
        for (int q = 0; q < 4; ++q)
          r[(mt * 16 + quad * 4 + q) * 49 + nt * 16 + l15] = acc[mt][nt][q];
  }
  __syncthreads();
  if (wave == 2 || wave == 3) {
    float* r = (wave == 3) ? red1 : red0;
#pragma unroll
    for (int mt = 0; mt < 3; ++mt)
#pragma unroll
      for (int nt = 0; nt < 3; ++nt)
#pragma unroll
        for (int q = 0; q < 4; ++q)
          r[(mt * 16 + quad * 4 + q) * 49 + nt * 16 + l15] += acc[mt][nt][q];
  }
  __syncthreads();
  if (wave == 4) {
#pragma unroll
    for (int mt = 0; mt < 3; ++mt)
#pragma unroll
      for (int nt = 0; nt < 3; ++nt)
#pragma unroll
        for (int q = 0; q < 4; ++q)
          red0[(mt * 16 + quad * 4 + q) * 49 + nt * 16 + l15] += acc[mt][nt][q];
  }
  __syncthreads();
  float* dst = y3p + (b * 32 + nc) * 1400;
  for (int idx = t; idx < 1400; idx += 320) {
    int o = idx / 35, p = idx % 35;
    dst[idx] = red0[p * 49 + o] + red1[p * 49 + o];
  }
}

// ---------------- k4: reduce 32 partials + bn2 + elu + projc -> y5 ----------------
__global__ __launch_bounds__(256) void k4_fused(const float* __restrict__ y3p,
                                                const float* __restrict__ ws,
                                                const float* __restrict__ projc_w,
                                                const float* __restrict__ projc_b,
                                                float* __restrict__ y5) {
  __shared__ float tls[1400];
  int t = threadIdx.x, b = blockIdx.x;
  for (int idx = t; idx < 1400; idx += 256) {
    float s = 0.f;
#pragma unroll 4
    for (int q = 0; q < 32; ++q) s += y3p[(b * 32 + q) * 1400 + idx];
    int o = idx / 35;
    float v = s * ws[WS_S2 + o] + ws[WS_SH2 + o];
    tls[idx] = v > 0.f ? v : __expf(v) - 1.f;
  }
  __syncthreads();
  for (int idx = t; idx < 1400; idx += 256) {
    int p = idx / 40, e = idx % 40;
    float acc = projc_b[e];
    for (int o = 0; o < 40; ++o) acc += tls[o * 35 + p] * projc_w[e * 40 + o];
    y5[b * 1400 + idx] = acc;
  }
}

// ---------------- k5: split-K FC1 partials ----------------
__global__ __launch_bounds__(256) void k5_fc1(const float* __restrict__ y5,
                                              const float* __restrict__ W1,
                                              float* __restrict__ zp) {
  __shared__ __align__(16) float yls[3200];
  int t = threadIdx.x;
  int nc = blockIdx.x, kc = blockIdx.y;  // (32, 7)
  for (int i = t; i < 800; i += 256) {
    int bb = i / 50, q = i % 50;
    ((float4*)yls)[bb * 50 + q] = *(const float4*)(y5 + bb * 1400 + kc * 200 + q * 4);
  }
  __syncthreads();
  int nl = t & 31, bg = t >> 5;
  int n = nc * 32 + nl;
  float acc0 = 0.f, acc1 = 0.f;
  const float* y0 = yls + (bg * 2) * 200;
  const float* y1 = yls + (bg * 2 + 1) * 200;
  for (int k = 0; k < 200; ++k) {
    float w = W1[(kc * 200 + k) * 1024 + n];
    acc0 += y0[k] * w;
    acc1 += y1[k] * w;
  }
  zp[(kc * 16 + bg * 2) * 1024 + n] = acc0;
  zp[(kc * 16 + bg * 2 + 1) * 1024 + n] = acc1;
}

// ---------------- k6: split-K FC2 partials, gelu(z) on the fly ----------------
__global__ __launch_bounds__(256) void k6_fc2(const float* __restrict__ zp,
                                              const float* __restrict__ b1,
                                              const float* __restrict__ W2,
                                              float* __restrict__ z2p) {
  __shared__ __align__(16) float gls[2048];
  int t = threadIdx.x;
  int nc = blockIdx.x, kc = blockIdx.y;  // (32, 8)
  for (int i = t; i < 2048; i += 256) {
    int bb = i >> 7, kk = i & 127;
    int np = kc * 128 + kk;
    float s = b1[np];
#pragma unroll
    for (int j = 0; j < 7; ++j) s += zp[(j * 16 + bb) * 1024 + np];
    gls[i] = 0.5f * s * (1.f + erff(s * 0.70710678f));
  }
  __syncthreads();
  int nl = t & 31, bg = t >> 5;
  int n = nc * 32 + nl;
  float acc0 = 0.f, acc1 = 0.f;
  const float* g0 = gls + (bg * 2) * 128;
  const float* g1 = gls + (bg * 2 + 1) * 128;
  for (int k = 0; k < 128; ++k) {
    float w = W2[(kc * 128 + k) * 1024 + n];
    acc0 += g0[k] * w;
    acc1 += g1[k] * w;
  }
  z2p[(kc * 16 + bg * 2) * 1024 + n] = acc0;
  z2p[(kc * 16 + bg * 2 + 1) * 1024 + n] = acc1;
}

// ---------------- k7: z recompute + FC2 reduce + residual + LayerNorm ----------------
__global__ __launch_bounds__(256) void k7_ln(const float* __restrict__ zp,
                                             const float* __restrict__ z2p,
                                             const float* __restrict__ b1,
                                             const float* __restrict__ b2,
                                             const float* __restrict__ ln_g,
                                             const float* __restrict__ ln_b,
                                             float* __restrict__ out) {
  __shared__ float r1[256], r2[256];
  int t = threadIdx.x, b = blockIdx.x;
  float4 v = *(const float4*)(b1 + t * 4);
  float4 bb2 = *(const float4*)(b2 + t * 4);
  v.x += bb2.x; v.y += bb2.y; v.z += bb2.z; v.w += bb2.w;
#pragma unroll
  for (int kc = 0; kc < 7; ++kc) {
    float4 p = *(const float4*)(zp + (kc * 16 + b) * 1024 + t * 4);
    v.x += p.x; v.y += p.y; v.z += p.z; v.w += p.w;
  }
#pragma unroll
  for (int kc = 0; kc < 8; ++kc) {
    float4 p = *(const float4*)(z2p + (kc * 16 + b) * 1024 + t * 4);
    v.x += p.x; v.y += p.y; v.z += p.z; v.w += p.w;
  }
  r1[t] = v.x + v.y + v.z + v.w;
  r2[t] = v.x * v.x + v.y * v.y + v.z * v.z + v.w * v.w;
  __syncthreads();
  for (int s = 128; s > 0; s >>= 1) {
    if (t < s) {
      r1[t] += r1[t + s];
      r2[t] += r2[t + s];
    }
    __syncthreads();
  }
  float mu = r1[0] * (1.f / 1024.f);
  float var = r2[0] * (1.f / 1024.f) - mu * mu;
  float rstd = rsqrtf(var + 1e-5f);
  float4 gg = *(const float4*)(ln_g + t * 4);
  float4 bb = *(const float4*)(ln_b + t * 4);
  float4 o;
  o.x = (v.x - mu) * rstd * gg.x + bb.x;
  o.y = (v.y - mu) * rstd * gg.y + bb.y;
  o.z = (v.z - mu) * rstd * gg.z + bb.z;
  o.w = (v.w - mu) * rstd * gg.w + bb.w;
  *(float4*)(out + b * 1024 + t * 4) = o;
}

extern "C" void kernel_launch(void* const* d_in, const int* in_sizes, int n_in,
                              void* d_out, int out_size, void* d_ws, size_t ws_size,
                              hipStream_t stream) {
  (void)in_sizes; (void)n_in; (void)out_size; (void)ws_size;
  const float* x       = (const float*)d_in[0];
  const float* gat_W   = (const float*)d_in[1];
  const float* att_src = (const float*)d_in[2];
  const float* att_dst = (const float*)d_in[3];
  const float* gat_b   = (const float*)d_in[4];
  const float* conv1_w = (const float*)d_in[5];
  const float* conv2_w = (const float*)d_in[11];
  const float* projc_w = (const float*)d_in[17];
  const float* projc_b = (const float*)d_in[18];
  const float* W1      = (const float*)d_in[19];
  const float* b1      = (const float*)d_in[20];
  const float* W2      = (const float*)d_in[21];
  const float* b2      = (const float*)d_in[22];
  const float* ln_g    = (const float*)d_in[23];
  const float* ln_b    = (const float*)d_in[24];
  float* ws  = (float*)d_ws;
  float* out = (float*)d_out;

  hipLaunchKernelGGL(k0_prep, dim3(993), dim3(256), 0, stream, gat_W, conv1_w,
                     (const float*)d_in[6], (const float*)d_in[7], (const float*)d_in[8],
                     (const float*)d_in[9], (const float*)d_in[10], (const float*)d_in[12],
                     (const float*)d_in[13], (const float*)d_in[14], (const float*)d_in[15],
                     (const float*)d_in[16], conv2_w, ws);
  hipLaunchKernelGGL(k1_mfma, dim3(256), dim3(256), 0, stream, x,
                     (const unsigned short*)(ws + WS_WPT), gat_b, ws + WS_H,
                     (unsigned short*)(ws + WS_HT), ws + WS_X1);
  hipLaunchKernelGGL(k1b_scores, dim3(256), dim3(256), 0, stream, ws + WS_H, att_src, att_dst,
                     ws + WS_AS, ws + WS_AD);
  hipLaunchKernelGGL(kP, dim3(1024), dim3(256), 0, stream, ws + WS_AS, ws + WS_AD,
                     (unsigned short*)(ws + WS_P));
  hipLaunchKernelGGL(kAttn, dim3(16, 4), dim3(256), 0, stream,
                     (const unsigned short*)(ws + WS_P),
                     (const unsigned short*)(ws + WS_HT), x, gat_b, ws + WS_X1);
  hipLaunchKernelGGL(k3_conv, dim3(16, 32), dim3(320), 0, stream, ws + WS_X1,
                     (const unsigned short*)(ws + WS_W2P),
                     (const unsigned short*)(ws + WS_WEFB), ws, ws + WS_Y3P);
  hipLaunchKernelGGL(k4_fused, dim3(16), dim3(256), 0, stream, ws + WS_Y3P, ws, projc_w,
                     projc_b, ws + WS_Y5);
  hipLaunchKernelGGL(k5_fc1, dim3(32, 7), dim3(256), 0, stream, ws + WS_Y5, W1, ws + WS_ZP);
  hipLaunchKernelGGL(k6_fc2, dim3(32, 8), dim3(256), 0, stream, ws + WS_ZP, b1, W2,
                     ws + WS_Z2P);
  hipLaunchKernelGGL(k7_ln, dim3(16), dim3(256), 0, stream, ws + WS_ZP, ws + WS_Z2P, b1, b2,
                     ln_g, ln_b, out);
}

// Round 13
// 232.174 us; speedup vs baseline: 1.3384x; 1.3384x over previous
//
#include <hip/hip_runtime.h>
#include <math.h>

typedef __attribute__((ext_vector_type(8))) short short8;
typedef __attribute__((ext_vector_type(4))) float f32x4;

__device__ __forceinline__ unsigned f2bf(float f) {
  unsigned u = __float_as_uint(f);
  return (u + 0x7FFFu + ((u >> 16) & 1u)) >> 16;
}
__device__ __forceinline__ unsigned pk2(float lo, float hi) {
  return f2bf(lo) | (f2bf(hi) << 16);
}

// ---------------- workspace layout (float offsets) ----------------
#define WS_X1    0                    // 16384*200
#define WS_W2P   3328000              // w2pre: 128*48*320 bf16 shorts
#define WS_AS    4966400              // 1024
#define WS_AD    4967424              // 1024
#define WS_WEFB  4968464              // weffB: 48*32 bf16
#define WS_S1    4969664              // 40
#define WS_SH1   4969704              // 40
#define WS_S2    4969744              // 40
#define WS_SH2   4969784              // 40
#define WS_H     4970496              // 1024*256 fp32
#define WS_P     5232640              // P bf16: 1024*1024 ushorts
#define WS_HT    5494784              // hT bf16: 256*1024 ushorts
#define WS_Y3P   WS_P                 // 16*32*1400 fp32 (overlays P/HT; dead by k3)
#define WS_Y5    8400768              // 16*1400
#define WS_ZP    8455936              // 7*16*1024
#define WS_Z2P   8570624              // 8*16*1024
#define WS_WPT   8701696              // 256*224 bf16
// end 8,730,368 floats = 34.9 MB

// ---------------- k0: params + wpadT + weffB + w2pre ----------------
__global__ __launch_bounds__(256) void k0_prep(const float* __restrict__ gat_W,
                        const float* __restrict__ conv1_w, const float* __restrict__ conv1_b,
                        const float* __restrict__ bn1_g, const float* __restrict__ bn1_b,
                        const float* __restrict__ bn1_m, const float* __restrict__ bn1_v,
                        const float* __restrict__ conv2_b,
                        const float* __restrict__ bn2_g, const float* __restrict__ bn2_b,
                        const float* __restrict__ bn2_m, const float* __restrict__ bn2_v,
                        const float* __restrict__ w2,
                        float* __restrict__ ws) {
  int bx = blockIdx.x, t = threadIdx.x;
  if (bx < 224) {
    unsigned short* wpt = (unsigned short*)(ws + WS_WPT);
    int idx = bx * 256 + t;
    int n = idx / 224, k = idx % 224;
    float v = (n < 200 && k < 200) ? gat_W[k * 200 + n] : 0.f;
    wpt[idx] = (unsigned short)f2bf(v);
    return;
  }
  if (bx == 224) {
    if (t < 48) {
      unsigned short* wb = (unsigned short*)(ws + WS_WEFB);
      float wv[30];
      if (t < 40) {
        for (int j = 0; j < 30; ++j) {
          float s = 0.f;
          for (int tt = 0; tt < 5; ++tt) {
            int k = j - tt;
            if (k >= 0 && k < 26) s += conv1_w[t * 26 + k];
          }
          wv[j] = s * 0.2f;
        }
      }
      for (int k = 0; k < 32; ++k)
        wb[t * 32 + k] = (unsigned short)f2bf((t < 40 && k < 30) ? wv[k] : 0.f);
    }
    if (t < 40) {
      float s1 = bn1_g[t] * rsqrtf(bn1_v[t] + 1e-5f);
      ws[WS_S1 + t] = s1;
      ws[WS_SH1 + t] = bn1_b[t] + (conv1_b[t] - bn1_m[t]) * s1;
      float s2 = bn2_g[t] * rsqrtf(bn2_v[t] + 1e-5f);
      ws[WS_S2 + t] = s2;
      ws[WS_SH2 + t] = bn2_b[t] + (conv2_b[t] - bn2_m[t]) * s2;
    }
    return;
  }
  __shared__ unsigned short lds[2560];
  int q = bx - 225;
  int c8 = q / 6, o0 = (q % 6) * 8;
  unsigned short* w2p = (unsigned short*)(ws + WS_W2P);
#pragma unroll
  for (int i = 0; i < 10; ++i) {
    int e = i * 256 + t;
    int o = e / 320, rr = e % 320;
    int c = rr / 8, nl = rr % 8;
    int oa = o0 + o;
    float v = (oa < 40) ? w2[(oa * 40 + c) * 1024 + c8 * 8 + nl] : 0.f;
    lds[o * 320 + nl * 40 + c] = (unsigned short)f2bf(v);
  }
  __syncthreads();
  uint4* src = (uint4*)lds;
  uint4* dst = (uint4*)(w2p + (c8 * 48 + o0) * 320);
  for (int i = t; i < 320; i += 256) dst[i] = src[i];
}

// ---------------- k1: MFMA GEMM, 256 blocks ----------------
__global__ __launch_bounds__(256) void k1_mfma(const float* __restrict__ x,
                                               const unsigned short* __restrict__ wpt,
                                               const float* __restrict__ gat_b,
                                               float* __restrict__ h,
                                               unsigned short* __restrict__ hT,
                                               float* __restrict__ x1) {
  __shared__ unsigned short As[64 * 232];
  __shared__ unsigned short Bt[64 * 232];
  int t = threadIdx.x;
  int wave = t >> 6, lane = t & 63;
  int m16 = lane & 15, quad = lane >> 4;
  int row0 = blockIdx.x * 64;
  {
    int m = t >> 2, kq = (t & 3) * 8;
    const float* xr = x + (row0 + m) * 200;
#pragma unroll
    for (int s = 0; s < 7; ++s) {
      int kg = s * 32 + kq;
      uint4 pv;
      if (kg + 8 <= 200) {
        float4 a = *(const float4*)(xr + kg);
        float4 b = *(const float4*)(xr + kg + 4);
        pv.x = pk2(a.x, a.y); pv.y = pk2(a.z, a.w);
        pv.z = pk2(b.x, b.y); pv.w = pk2(b.z, b.w);
      } else {
        float e[8];
#pragma unroll
        for (int q = 0; q < 8; ++q) e[q] = (kg + q < 200) ? xr[kg + q] : 0.f;
        pv.x = pk2(e[0], e[1]); pv.y = pk2(e[2], e[3]);
        pv.z = pk2(e[4], e[5]); pv.w = pk2(e[6], e[7]);
      }
      *(uint4*)&As[m * 232 + kg] = pv;
    }
  }
  __syncthreads();
  for (int c = 0; c < 4; ++c) {
    int n0 = c * 64;
    for (int i = t; i < 1792; i += 256) {
      int row = i / 28, ch = i % 28;
      *(short8*)&Bt[row * 232 + ch * 8] = *(const short8*)&wpt[(n0 + row) * 224 + ch * 8];
    }
    __syncthreads();
    f32x4 acc[4];
#pragma unroll
    for (int nt = 0; nt < 4; ++nt) acc[nt] = (f32x4){0.f, 0.f, 0.f, 0.f};
#pragma unroll
    for (int s = 0; s < 7; ++s) {
      short8 af = *(const short8*)&As[(wave * 16 + m16) * 232 + s * 32 + quad * 8];
      int kb = s * 32 + quad * 8;
#pragma unroll
      for (int nt = 0; nt < 4; ++nt) {
        short8 bf = *(const short8*)&Bt[(nt * 16 + m16) * 232 + kb];
        acc[nt] = __builtin_amdgcn_mfma_f32_16x16x32_bf16(af, bf, acc[nt], 0, 0, 0);
      }
    }
    if (blockIdx.x < 16) {
#pragma unroll
      for (int nt = 0; nt < 4; ++nt) {
        int col = n0 + nt * 16 + m16;
#pragma unroll
        for (int r = 0; r < 4; ++r) {
          int row = row0 + wave * 16 + quad * 4 + r;
          float v = acc[nt][r];
          h[row * 256 + col] = v;
          hT[col * 1024 + row] = (unsigned short)f2bf(v);
        }
      }
    } else {
#pragma unroll
      for (int nt = 0; nt < 4; ++nt) {
        int col = n0 + nt * 16 + m16;
        if (col < 200) {
          float gb = gat_b[col];
#pragma unroll
          for (int r = 0; r < 4; ++r) {
            int row = row0 + wave * 16 + quad * 4 + r;
            x1[row * 200 + col] = x[row * 200 + col] + acc[nt][r] + gb;
          }
        }
      }
    }
    __syncthreads();
  }
}

// ---------------- k1b: attention scores — wave-per-row ----------------
__global__ __launch_bounds__(256) void k1b_scores(const float* __restrict__ h,
                                                  const float* __restrict__ att_src,
                                                  const float* __restrict__ att_dst,
                                                  float* __restrict__ as_,
                                                  float* __restrict__ ad_) {
  int t = threadIdx.x;
  int wave = t >> 6, lane = t & 63;
  int r = blockIdx.x * 4 + wave;
  float s = 0.f, d = 0.f;
  if (lane < 50) {
    float4 v = *(const float4*)(h + r * 256 + lane * 4);
    float4 a = *(const float4*)(att_src + lane * 4);
    float4 dd = *(const float4*)(att_dst + lane * 4);
    s = v.x * a.x + v.y * a.y + v.z * a.z + v.w * a.w;
    d = v.x * dd.x + v.y * dd.y + v.z * dd.z + v.w * dd.w;
  }
#pragma unroll
  for (int off = 32; off > 0; off >>= 1) {
    s += __shfl_down(s, off);
    d += __shfl_down(d, off);
  }
  if (lane == 0) {
    as_[r] = s;
    ad_[r] = d;
  }
}

// ---------------- kP: normalized softmax P -> bf16 ----------------
__global__ __launch_bounds__(256) void kP(const float* __restrict__ as_,
                                          const float* __restrict__ ad_,
                                          unsigned short* __restrict__ Pb) {
  __shared__ float rb[256];
  int t = threadIdx.x, i = blockIdx.x;
  float a0 = as_[t], a1 = as_[256 + t], a2 = as_[512 + t], a3 = as_[768 + t];
  rb[t] = fmaxf(fmaxf(a0, a1), fmaxf(a2, a3));
  __syncthreads();
  for (int st = 128; st > 0; st >>= 1) {
    if (t < st) rb[t] = fmaxf(rb[t], rb[t + st]);
    __syncthreads();
  }
  float maxs = rb[0];
  __syncthreads();
  float ad = ad_[i];
  float mv = maxs + ad;
  float M = mv >= 0.f ? mv : 0.2f * mv;
  float av[4] = {a0, a1, a2, a3};
  float p[4];
  float s = 0.f;
#pragma unroll
  for (int q = 0; q < 4; ++q) {
    float v = av[q] + ad;
    float l = v >= 0.f ? v : 0.2f * v;
    p[q] = __expf(l - M);
    s += p[q];
  }
  rb[t] = s;
  __syncthreads();
  for (int st = 128; st > 0; st >>= 1) {
    if (t < st) rb[t] += rb[t + st];
    __syncthreads();
  }
  float inv = 1.f / rb[0];
#pragma unroll
  for (int q = 0; q < 4; ++q)
    Pb[i * 1024 + q * 256 + t] = (unsigned short)f2bf(p[q] * inv);
}

// ---------------- kAttn v3: 256 blocks, waves split K, LDS reduce, fused residual ----
// grid (64 i-tiles of 16, 4 f-tiles of 64), block 256 (4 waves).
__global__ __launch_bounds__(256) void kAttn(const unsigned short* __restrict__ Pb,
                                             const unsigned short* __restrict__ hT,
                                             const float* __restrict__ x,
                                             const float* __restrict__ gat_b,
                                             float* __restrict__ x1) {
  __shared__ float red[4][1024];  // 16 KB: per-wave 16x64 C tile
  int t = threadIdx.x;
  int wave = t >> 6, lane = t & 63;
  int l15 = lane & 15, quad = lane >> 4;
  int i0 = blockIdx.x * 16, f0 = blockIdx.y * 64;
  int arow = i0 + l15;
  f32x4 acc[4];
#pragma unroll
  for (int nt = 0; nt < 4; ++nt) acc[nt] = (f32x4){0.f, 0.f, 0.f, 0.f};
#pragma unroll
  for (int ks = 0; ks < 8; ++ks) {
    int koff = wave * 256 + ks * 32 + quad * 8;
    short8 a = *(const short8*)&Pb[arow * 1024 + koff];
#pragma unroll
    for (int nt = 0; nt < 4; ++nt) {
      short8 bf = *(const short8*)&hT[(f0 + nt * 16 + l15) * 1024 + koff];
      acc[nt] = __builtin_amdgcn_mfma_f32_16x16x32_bf16(a, bf, acc[nt], 0, 0, 0);
    }
  }
#pragma unroll
  for (int nt = 0; nt < 4; ++nt)
#pragma unroll
    for (int r = 0; r < 4; ++r)
      red[wave][(quad * 4 + r) * 64 + nt * 16 + l15] = acc[nt][r];
  __syncthreads();
  // 256 threads x 4 elems: reduce 4 waves + residual
#pragma unroll
  for (int e = 0; e < 4; ++e) {
    int idx = t * 4 + e;          // wrong stride for coalescing? idx in [0,1024)
    int row = idx >> 6, col = idx & 63;
    int cg = f0 + col;
    if (cg < 200) {
      float s = red[0][idx] + red[1][idx] + red[2][idx] + red[3][idx];
      int rg = i0 + row;
      x1[rg * 200 + cg] = x[rg * 200 + cg] + s + gat_b[cg];
    }
  }
}

// ---------------- k3 v12: static-unrolled (no dynamic c4 indexing), t2 aliases tA ----
// grid (16 b, 32 nc), block 320 (5 waves). conv2 acc persists across 4 chunks.
// Wave 4 computes 2 garbage m-tiles (mi=2,3): reads stay inside smem, results
// masked by m<280. This keeps the mi loop compile-time so c4[][] stays in VGPRs
// (R12's runtime-bound loop put c4 in scratch: 113 MB spill traffic).
__global__ __launch_bounds__(320, 2) void k3_conv(const float* __restrict__ x1,
                                                  const unsigned short* __restrict__ w2pre,
                                                  const unsigned short* __restrict__ weffB,
                                                  const float* __restrict__ ws,
                                                  float* __restrict__ y3p) {
  __shared__ __align__(16) char smem[30016];
  float* xbp = (float*)smem;                              // 8 x 200 fp32
  unsigned short* tA = (unsigned short*)(smem + 6400);    // 288 x 32 bf16
  unsigned short* t2 = (unsigned short*)(smem + 6400);    // 36 x 328 bf16 — ALIASES tA
  int t = threadIdx.x;
  int b = blockIdx.x, nc = blockIdx.y;
  int wave = t >> 6, lane = t & 63;
  int l15 = lane & 15, quad = lane >> 4;
  short8 bw[3];
  float s1v[3], sh1v[3];
#pragma unroll
  for (int nt = 0; nt < 3; ++nt) {
    bw[nt] = *(const short8*)&weffB[(nt * 16 + l15) * 32 + quad * 8];
    int c = nt * 16 + l15;
    s1v[nt] = (c < 40) ? ws[WS_S1 + c] : 0.f;
    sh1v[nt] = (c < 40) ? ws[WS_SH1 + c] : 0.f;
  }
  f32x4 acc[3][3];
#pragma unroll
  for (int mt = 0; mt < 3; ++mt)
#pragma unroll
    for (int nt = 0; nt < 3; ++nt) acc[mt][nt] = (f32x4){0.f, 0.f, 0.f, 0.f};
  int mt0 = wave * 4;
  {
    int n0 = nc * 32;
    for (int i = t; i < 400; i += 320) {
      int nn = i / 50, q = i % 50;
      ((float4*)(xbp + nn * 200))[q] = ((const float4*)(x1 + (b * 1024 + n0 + nn) * 200))[q];
    }
  }
  __syncthreads();
  for (int it = 0; it < 4; ++it) {
    int c8 = nc * 4 + it;
    if (t < 280) {
      int nn = t / 35, p = t % 35;
      const float* xr = xbp + nn * 200 + p * 5;
      uint pv[16];
#pragma unroll
      for (int kk = 0; kk < 15; ++kk) pv[kk] = pk2(xr[kk * 2], xr[kk * 2 + 1]);
      pv[15] = 0u;
      uint4* dst = (uint4*)(tA + t * 32);
      dst[0] = make_uint4(pv[0], pv[1], pv[2], pv[3]);
      dst[1] = make_uint4(pv[4], pv[5], pv[6], pv[7]);
      dst[2] = make_uint4(pv[8], pv[9], pv[10], pv[11]);
      dst[3] = make_uint4(pv[12], pv[13], pv[14], pv[15]);
    } else if (t < 288) {
      uint4 z = make_uint4(0u, 0u, 0u, 0u);
      uint4* dst = (uint4*)(tA + t * 32);
      dst[0] = z; dst[1] = z; dst[2] = z; dst[3] = z;
    }
    __syncthreads();
    // conv1 MFMA -> C in regs (STATIC mi unroll; wave4 mi>=2 garbage, masked later)
    f32x4 c4[4][3];
#pragma unroll
    for (int mi = 0; mi < 4; ++mi) {
      int row = (mt0 + mi) * 16 + l15;
      row = row > 303 ? 303 : row;  // clamp inside tA's 304-row-safe span
      short8 a = *(const short8*)&tA[row * 32 + quad * 8];
#pragma unroll
      for (int nt = 0; nt < 3; ++nt) {
        f32x4 z = {0.f, 0.f, 0.f, 0.f};
        c4[mi][nt] = __builtin_amdgcn_mfma_f32_16x16x32_bf16(a, bw[nt], z, 0, 0, 0);
      }
    }
    __syncthreads();  // tA reads done; t2 may overwrite
#pragma unroll
    for (int mi = 0; mi < 4; ++mi) {
      int mt = mt0 + mi;
#pragma unroll
      for (int nt = 0; nt < 3; ++nt) {
        int c = nt * 16 + l15;
        if (c >= 40) continue;
#pragma unroll
        for (int r = 0; r < 4; ++r) {
          int m = mt * 16 + quad * 4 + r;
          if (m < 280) {
            float v = c4[mi][nt][r] * s1v[nt] + sh1v[nt];
            float e = v > 0.f ? v : __expf(v) - 1.f;
            int p = m % 35, nn = m / 35;
            t2[p * 328 + nn * 40 + c] = (unsigned short)f2bf(e);
          }
        }
      }
    }
    __syncthreads();  // t2 ready
    if (it < 3) {
      int n0n = nc * 32 + (it + 1) * 8;
      for (int i = t; i < 400; i += 320) {
        int nn = i / 50, q = i % 50;
        ((float4*)(xbp + nn * 200))[q] = ((const float4*)(x1 + (b * 1024 + n0n + nn) * 200))[q];
      }
    }
    const unsigned short* bbase = w2pre + c8 * 48 * 320;
#pragma unroll
    for (int ks = 0; ks < 2; ++ks) {
      int koff = wave * 64 + ks * 32 + quad * 8;
      short8 a[3], bb[3];
#pragma unroll
      for (int mt = 0; mt < 3; ++mt) {
        int row = mt * 16 + l15;
        row = row > 35 ? 35 : row;
        a[mt] = *(const short8*)&t2[row * 328 + koff];
      }
#pragma unroll
      for (int nt = 0; nt < 3; ++nt)
        bb[nt] = *(const short8*)&bbase[(nt * 16 + l15) * 320 + koff];
#pragma unroll
      for (int mt = 0; mt < 3; ++mt)
#pragma unroll
        for (int nt = 0; nt < 3; ++nt)
          acc[mt][nt] = __builtin_amdgcn_mfma_f32_16x16x32_bf16(a[mt], bb[nt], acc[mt][nt], 0, 0, 0);
    }
    __syncthreads();
  }
  float* red0 = (float*)smem;
  float* red1 = red0 + 48 * 49;
  if (wave < 2) {
    float* r = wave ? red1 : red0;
#pragma unroll
    for (int mt = 0; mt < 3; ++mt)
#pragma unroll
      for (int nt = 0; nt < 3; ++nt)
#pragma unroll
        for (int q = 0; q < 4; ++q)
          r[(mt * 16 + quad * 4 + q) * 49 + nt * 16 + l15] = acc[mt][nt][q];
  }
  __syncthreads();
  if (wave == 2 || wave == 3) {
    float* r = (wave == 3) ? red1 : red0;
#pragma unroll
    for (int mt = 0; mt < 3; ++mt)
#pragma unroll
      for (int nt = 0; nt < 3; ++nt)
#pragma unroll
        for (int q = 0; q < 4; ++q)
          r[(mt * 16 + quad * 4 + q) * 49 + nt * 16 + l15] += acc[mt][nt][q];
  }
  __syncthreads();
  if (wave == 4) {
#pragma unroll
    for (int mt = 0; mt < 3; ++mt)
#pragma unroll
      for (int nt = 0; nt < 3; ++nt)
#pragma unroll
        for (int q = 0; q < 4; ++q)
          red0[(mt * 16 + quad * 4 + q) * 49 + nt * 16 + l15] += acc[mt][nt][q];
  }
  __syncthreads();
  float* dst = y3p + (b * 32 + nc) * 1400;
  for (int idx = t; idx < 1400; idx += 320) {
    int o = idx / 35, p = idx % 35;
    dst[idx] = red0[p * 49 + o] + red1[p * 49 + o];
  }
}

// ---------------- k4: reduce 32 partials + bn2 + elu + projc -> y5 ----------------
__global__ __launch_bounds__(256) void k4_fused(const float* __restrict__ y3p,
                                                const float* __restrict__ ws,
                                                const float* __restrict__ projc_w,
                                                const float* __restrict__ projc_b,
                                                float* __restrict__ y5) {
  __shared__ float tls[1400];
  int t = threadIdx.x, b = blockIdx.x;
  for (int idx = t; idx < 1400; idx += 256) {
    float s = 0.f;
#pragma unroll 4
    for (int q = 0; q < 32; ++q) s += y3p[(b * 32 + q) * 1400 + idx];
    int o = idx / 35;
    float v = s * ws[WS_S2 + o] + ws[WS_SH2 + o];
    tls[idx] = v > 0.f ? v : __expf(v) - 1.f;
  }
  __syncthreads();
  for (int idx = t; idx < 1400; idx += 256) {
    int p = idx / 40, e = idx % 40;
    float acc = projc_b[e];
    for (int o = 0; o < 40; ++o) acc += tls[o * 35 + p] * projc_w[e * 40 + o];
    y5[b * 1400 + idx] = acc;
  }
}

// ---------------- k5: split-K FC1 partials ----------------
__global__ __launch_bounds__(256) void k5_fc1(const float* __restrict__ y5,
                                              const float* __restrict__ W1,
                                              float* __restrict__ zp) {
  __shared__ __align__(16) float yls[3200];
  int t = threadIdx.x;
  int nc = blockIdx.x, kc = blockIdx.y;  // (32, 7)
  for (int i = t; i < 800; i += 256) {
    int bb = i / 50, q = i % 50;
    ((float4*)yls)[bb * 50 + q] = *(const float4*)(y5 + bb * 1400 + kc * 200 + q * 4);
  }
  __syncthreads();
  int nl = t & 31, bg = t >> 5;
  int n = nc * 32 + nl;
  float acc0 = 0.f, acc1 = 0.f;
  const float* y0 = yls + (bg * 2) * 200;
  const float* y1 = yls + (bg * 2 + 1) * 200;
  for (int k = 0; k < 200; ++k) {
    float w = W1[(kc * 200 + k) * 1024 + n];
    acc0 += y0[k] * w;
    acc1 += y1[k] * w;
  }
  zp[(kc * 16 + bg * 2) * 1024 + n] = acc0;
  zp[(kc * 16 + bg * 2 + 1) * 1024 + n] = acc1;
}

// ---------------- k6: split-K FC2 partials, gelu(z) on the fly ----------------
__global__ __launch_bounds__(256) void k6_fc2(const float* __restrict__ zp,
                                              const float* __restrict__ b1,
                                              const float* __restrict__ W2,
                                              float* __restrict__ z2p) {
  __shared__ __align__(16) float gls[2048];
  int t = threadIdx.x;
  int nc = blockIdx.x, kc = blockIdx.y;  // (32, 8)
  for (int i = t; i < 2048; i += 256) {
    int bb = i >> 7, kk = i & 127;
    int np = kc * 128 + kk;
    float s = b1[np];
#pragma unroll
    for (int j = 0; j < 7; ++j) s += zp[(j * 16 + bb) * 1024 + np];
    gls[i] = 0.5f * s * (1.f + erff(s * 0.70710678f));
  }
  __syncthreads();
  int nl = t & 31, bg = t >> 5;
  int n = nc * 32 + nl;
  float acc0 = 0.f, acc1 = 0.f;
  const float* g0 = gls + (bg * 2) * 128;
  const float* g1 = gls + (bg * 2 + 1) * 128;
  for (int k = 0; k < 128; ++k) {
    float w = W2[(kc * 128 + k) * 1024 + n];
    acc0 += g0[k] * w;
    acc1 += g1[k] * w;
  }
  z2p[(kc * 16 + bg * 2) * 1024 + n] = acc0;
  z2p[(kc * 16 + bg * 2 + 1) * 1024 + n] = acc1;
}

// ---------------- k7: z recompute + FC2 reduce + residual + LayerNorm ----------------
__global__ __launch_bounds__(256) void k7_ln(const float* __restrict__ zp,
                                             const float* __restrict__ z2p,
                                             const float* __restrict__ b1,
                                             const float* __restrict__ b2,
                                             const float* __restrict__ ln_g,
                                             const float* __restrict__ ln_b,
                                             float* __restrict__ out) {
  __shared__ float r1[256], r2[256];
  int t = threadIdx.x, b = blockIdx.x;
  float4 v = *(const float4*)(b1 + t * 4);
  float4 bb2 = *(const float4*)(b2 + t * 4);
  v.x += bb2.x; v.y += bb2.y; v.z += bb2.z; v.w += bb2.w;
#pragma unroll
  for (int kc = 0; kc < 7; ++kc) {
    float4 p = *(const float4*)(zp + (kc * 16 + b) * 1024 + t * 4);
    v.x += p.x; v.y += p.y; v.z += p.z; v.w += p.w;
  }
#pragma unroll
  for (int kc = 0; kc < 8; ++kc) {
    float4 p = *(const float4*)(z2p + (kc * 16 + b) * 1024 + t * 4);
    v.x += p.x; v.y += p.y; v.z += p.z; v.w += p.w;
  }
  r1[t] = v.x + v.y + v.z + v.w;
  r2[t] = v.x * v.x + v.y * v.y + v.z * v.z + v.w * v.w;
  __syncthreads();
  for (int s = 128; s > 0; s >>= 1) {
    if (t < s) {
      r1[t] += r1[t + s];
      r2[t] += r2[t + s];
    }
    __syncthreads();
  }
  float mu = r1[0] * (1.f / 1024.f);
  float var = r2[0] * (1.f / 1024.f) - mu * mu;
  float rstd = rsqrtf(var + 1e-5f);
  float4 gg = *(const float4*)(ln_g + t * 4);
  float4 bb = *(const float4*)(ln_b + t * 4);
  float4 o;
  o.x = (v.x - mu) * rstd * gg.x + bb.x;
  o.y = (v.y - mu) * rstd * gg.y + bb.y;
  o.z = (v.z - mu) * rstd * gg.z + bb.z;
  o.w = (v.w - mu) * rstd * gg.w + bb.w;
  *(float4*)(out + b * 1024 + t * 4) = o;
}

extern "C" void kernel_launch(void* const* d_in, const int* in_sizes, int n_in,
                              void* d_out, int out_size, void* d_ws, size_t ws_size,
                              hipStream_t stream) {
  (void)in_sizes; (void)n_in; (void)out_size; (void)ws_size;
  const float* x       = (const float*)d_in[0];
  const float* gat_W   = (const float*)d_in[1];
  const float* att_src = (const float*)d_in[2];
  const float* att_dst = (const float*)d_in[3];
  const float* gat_b   = (const float*)d_in[4];
  const float* conv1_w = (const float*)d_in[5];
  const float* conv2_w = (const float*)d_in[11];
  const float* projc_w = (const float*)d_in[17];
  const float* projc_b = (const float*)d_in[18];
  const float* W1      = (const float*)d_in[19];
  const float* b1      = (const float*)d_in[20];
  const float* W2      = (const float*)d_in[21];
  const float* b2      = (const float*)d_in[22];
  const float* ln_g    = (const float*)d_in[23];
  const float* ln_b    = (const float*)d_in[24];
  float* ws  = (float*)d_ws;
  float* out = (float*)d_out;

  hipLaunchKernelGGL(k0_prep, dim3(993), dim3(256), 0, stream, gat_W, conv1_w,
                     (const float*)d_in[6], (const float*)d_in[7], (const float*)d_in[8],
                     (const float*)d_in[9], (const float*)d_in[10], (const float*)d_in[12],
                     (const float*)d_in[13], (const float*)d_in[14], (const float*)d_in[15],
                     (const float*)d_in[16], conv2_w, ws);
  hipLaunchKernelGGL(k1_mfma, dim3(256), dim3(256), 0, stream, x,
                     (const unsigned short*)(ws + WS_WPT), gat_b, ws + WS_H,
                     (unsigned short*)(ws + WS_HT), ws + WS_X1);
  hipLaunchKernelGGL(k1b_scores, dim3(256), dim3(256), 0, stream, ws + WS_H, att_src, att_dst,
                     ws + WS_AS, ws + WS_AD);
  hipLaunchKernelGGL(kP, dim3(1024), dim3(256), 0, stream, ws + WS_AS, ws + WS_AD,
                     (unsigned short*)(ws + WS_P));
  hipLaunchKernelGGL(kAttn, dim3(64, 4), dim3(256), 0, stream,
                     (const unsigned short*)(ws + WS_P),
                     (const unsigned short*)(ws + WS_HT), x, gat_b, ws + WS_X1);
  hipLaunchKernelGGL(k3_conv, dim3(16, 32), dim3(320), 0, stream, ws + WS_X1,
                     (const unsigned short*)(ws + WS_W2P),
                     (const unsigned short*)(ws + WS_WEFB), ws, ws + WS_Y3P);
  hipLaunchKernelGGL(k4_fused, dim3(16), dim3(256), 0, stream, ws + WS_Y3P, ws, projc_w,
                     projc_b, ws + WS_Y5);
  hipLaunchKernelGGL(k5_fc1, dim3(32, 7), dim3(256), 0, stream, ws + WS_Y5, W1, ws + WS_ZP);
  hipLaunchKernelGGL(k6_fc2, dim3(32, 8), dim3(256), 0, stream, ws + WS_ZP, b1, W2,
                     ws + WS_Z2P);
  hipLaunchKernelGGL(k7_ln, dim3(16), dim3(256), 0, stream, ws + WS_ZP, ws + WS_Z2P, b1, b2,
                     ln_g, ln_b, out);
}